// Round 15
// baseline (491.267 us; speedup 1.0000x reference)
//
#include <hip/hip_runtime.h>
#include <hip/hip_bf16.h>

// B=8, C=128, N=16384, NH=8, HD=16, D=128
#define N_SEQ 16384
#define EPSF 1e-6f

typedef unsigned short u16;
typedef unsigned int   u32;
typedef __attribute__((ext_vector_type(8))) __bf16 bf16x8;
typedef __attribute__((ext_vector_type(4))) float  f32x4;

union B8 { u32 w[4]; bf16x8 v; };

__device__ __forceinline__ int rfl(int x){ return __builtin_amdgcn_readfirstlane(x); }
__device__ __forceinline__ u16 f2b(float x){
  union { __hip_bfloat16 h; u16 u; } c; c.h = __float2bfloat16(x); return c.u;
}
__device__ __forceinline__ u32 pk2(float a, float b){
  return (u32)f2b(a) | ((u32)f2b(b) << 16);
}
__device__ __forceinline__ float bf2f(u16 v){ return __uint_as_float(((u32)v) << 16); }
#define MFMA(a,b,c) __builtin_amdgcn_mfma_f32_16x16x32_bf16((a),(b),(c),0,0,0)

// Swizzled LDS indexers (u16 units): linear rows, idx ^= (row&7)<<3.
__device__ __forceinline__ int xidx(int n, int f){ return n*128 + (f ^ ((n & 7) << 3)); } // [64 n][128 f]
__device__ __forceinline__ int kidx(int d, int n){ return d*64  + (n ^ ((d & 7) << 3)); } // [128 d][64 n]

#define QTS 24   // u16 stride of Qt rows (48B: 16B-aligned for ds_read_b128)

// 16-row GEMM (pass1): q[nt] += W @ X.
__device__ __forceinline__ void gemmW(const u16* __restrict__ Wb, int row, int ldw, int koff,
                                      const u16* __restrict__ Xl, int m, int g, f32x4 q[4]){
  #pragma unroll
  for (int ks = 0; ks < 4; ++ks){
    const bf16x8 av = *reinterpret_cast<const bf16x8*>(&Wb[(size_t)row*ldw + koff + ks*32 + g*8]);
    #pragma unroll
    for (int nt = 0; nt < 4; ++nt){
      const bf16x8 bv = *reinterpret_cast<const bf16x8*>(&Xl[xidx(nt*16+m, ks*32 + g*8)]);
      q[nt] = MFMA(av, bv, q[nt]);
    }
  }
}

// 2x2-blocked GEMM (pass2): wave owns rows rb32..+31 x cols CB..+31.
// Each LDS B-read feeds 2 MFMAs, each A-read feeds 2 MFMAs (16 MFMA, 8 B-reads, 8 A-loads).
// Accumulator footprint identical to the 16-row form (16 f32/lane).
__device__ __forceinline__ void gemm22(const u16* __restrict__ Wb, int rb32, int ldw, int koff,
                                       const u16* __restrict__ Xl, int CB, int m, int g,
                                       f32x4 (&q)[2][2]){
  #pragma unroll
  for (int ks = 0; ks < 4; ++ks){
    const bf16x8 av0 = *reinterpret_cast<const bf16x8*>(
        &Wb[(size_t)(rb32 + m)*ldw + koff + ks*32 + g*8]);
    const bf16x8 av1 = *reinterpret_cast<const bf16x8*>(
        &Wb[(size_t)(rb32 + 16 + m)*ldw + koff + ks*32 + g*8]);
    const bf16x8 bv0 = *reinterpret_cast<const bf16x8*>(&Xl[xidx(CB + m,      ks*32 + g*8)]);
    const bf16x8 bv1 = *reinterpret_cast<const bf16x8*>(&Xl[xidx(CB + 16 + m, ks*32 + g*8)]);
    q[0][0] = MFMA(av0, bv0, q[0][0]);
    q[0][1] = MFMA(av0, bv1, q[0][1]);
    q[1][0] = MFMA(av1, bv0, q[1][0]);
    q[1][1] = MFMA(av1, bv1, q[1][1]);
  }
}

// One attention+Wback stage. Wave: rows rb32..rb32+31 (heads 2W, 2W+1), cols CB..CB+31.
// T master in Xl (bf16, owner-thread RMW). 2 barriers. Accumulator totals match R8 exactly.
template<int NSRC>
__device__ __forceinline__ void stage(u16* Xl, u16* Ul, u16* Qt,
    const u16* __restrict__ wqb, const u16* __restrict__ wbb,
    const u32* __restrict__ kvb, const float* __restrict__ ksf,
    int s1, int s2, int b, int W, int CB, int rb32, int g, int m){
  // qh = relu(Wq @ T) + eps : 2x2 tiles (rt = head j, ct = col half)
  f32x4 q[2][2];
  #pragma unroll
  for (int rt = 0; rt < 2; ++rt)
    #pragma unroll
    for (int ct = 0; ct < 2; ++ct) q[rt][ct] = (f32x4){0.f,0.f,0.f,0.f};
  gemm22(wqb, rb32, 128, 0, Xl, CB, m, g, q);
  #pragma unroll
  for (int rt = 0; rt < 2; ++rt)
    #pragma unroll
    for (int ct = 0; ct < 2; ++ct)
      #pragma unroll
      for (int r = 0; r < 4; ++r) q[rt][ct][r] = fmaxf(q[rt][ct][r], 0.f) + EPSF;
  // attention per head j (rows rb32+16j..+15), per ct col-half
  #pragma unroll
  for (int j = 0; j < 2; ++j){
    const int h = 2*W + j;
    const int sA = ((s1*8 + b)*8 + h);
    const int sB = ((s2*8 + b)*8 + h);
    float4 ksA = *reinterpret_cast<const float4*>(ksf + sA*16 + 4*g);
    float4 ksB = ksA;
    B8 kA, kB;
    uint4 a4 = *reinterpret_cast<const uint4*>(&kvb[sA*128 + (g&1)*64 + m*4]);
    kA.w[0]=a4.x; kA.w[1]=a4.y; kA.w[2]=a4.z; kA.w[3]=a4.w;
    if (NSRC == 2){
      ksB = *reinterpret_cast<const float4*>(ksf + sB*16 + 4*g);
      uint4 b4 = *reinterpret_cast<const uint4*>(&kvb[sB*128 + (g&1)*64 + m*4]);
      kB.w[0]=b4.x; kB.w[1]=b4.y; kB.w[2]=b4.z; kB.w[3]=b4.w;
    }
    u16* qrow = Qt + h*(64*QTS);
    #pragma unroll
    for (int ct = 0; ct < 2; ++ct){
      const int n = CB + ct*16 + m;
      float q0 = q[j][ct][0], q1 = q[j][ct][1], q2 = q[j][ct][2], q3 = q[j][ct][3];
      float p1 = q0*ksA.x + q1*ksA.y + q2*ksA.z + q3*ksA.w;
      p1 += __shfl_xor(p1, 16); p1 += __shfl_xor(p1, 32);
      float z1 = 1.0f / (p1 + EPSF);
      float z2 = 0.f;
      if (NSRC == 2){
        float p2 = q0*ksB.x + q1*ksB.y + q2*ksB.z + q3*ksB.w;
        p2 += __shfl_xor(p2, 16); p2 += __shfl_xor(p2, 32);
        z2 = 1.0f / (p2 + EPSF);
      }
      // qh^T into Qt[h][n][d]: lane owns d=4g..4g+3 at col n
      *reinterpret_cast<uint2*>(&qrow[n*QTS + 4*g]) =
        make_uint2(pk2(q0, q1), pk2(q2, q3));
      // PV: B[k=d][col] = Qt[n=...][d=g*8..] (g<2; k>=16 zero-padded); within-wave prod/cons
      B8 bb;
      if (g < 2) bb.v = *reinterpret_cast<const bf16x8*>(&qrow[n*QTS + g*8]);
      else { bb.w[0]=0u; bb.w[1]=0u; bb.w[2]=0u; bb.w[3]=0u; }
      const f32x4 z4 = (f32x4){0.f,0.f,0.f,0.f};
      f32x4 Uv = MFMA(kA.v, bb.v, z4) * z1;
      if (NSRC == 2) Uv += MFMA(kB.v, bb.v, z4) * z2;
      *reinterpret_cast<uint2*>(&Ul[xidx(n, rb32 + 16*j + 4*g)]) =
        make_uint2(pk2(Uv[0], Uv[1]), pk2(Uv[2], Uv[3]));
    }
  }
  // preload old T into Wback accumulator (MFMA C-in does the add); Xl stable until store
  f32x4 t4[2][2];
  #pragma unroll
  for (int rt = 0; rt < 2; ++rt)
    #pragma unroll
    for (int ct = 0; ct < 2; ++ct){
      uint2 old = *reinterpret_cast<const uint2*>(
          &Xl[xidx(CB + ct*16 + m, rb32 + rt*16 + 4*g)]);
      t4[rt][ct][0] = bf2f((u16)(old.x & 0xffffu));
      t4[rt][ct][1] = bf2f((u16)(old.x >> 16));
      t4[rt][ct][2] = bf2f((u16)(old.y & 0xffffu));
      t4[rt][ct][3] = bf2f((u16)(old.y >> 16));
    }
  __syncthreads();
  // T += Wback @ U
  gemm22(wbb, rb32, 128, 0, Ul, CB, m, g, t4);
  #pragma unroll
  for (int rt = 0; rt < 2; ++rt)
    #pragma unroll
    for (int ct = 0; ct < 2; ++ct)
      *reinterpret_cast<uint2*>(&Xl[xidx(CB + ct*16 + m, rb32 + rt*16 + 4*g)]) =
        make_uint2(pk2(t4[rt][ct][0], t4[rt][ct][1]), pk2(t4[rt][ct][2], t4[rt][ct][3]));
  __syncthreads();
}

// ---------------- Prepack: all weights -> bf16 row-major (MFMA-ready) ------------------------------
__global__ void k_prepack(const float* __restrict__ Wq, const float* __restrict__ Wk,
                          const float* __restrict__ Wv, const float* __restrict__ Wb,
                          const float* __restrict__ Wo,
                          u16* __restrict__ wqb, u16* __restrict__ wkb, u16* __restrict__ wvb,
                          u16* __restrict__ wbb, u16* __restrict__ wob){
  int i = blockIdx.x*256 + threadIdx.x;     // grid 448*256 = 114688
  if      (i < 16384) wqb[i]         = f2b(Wq[i]);
  else if (i < 32768) wkb[i - 16384] = f2b(Wk[i - 16384]);
  else if (i < 49152) wvb[i - 32768] = f2b(Wv[i - 32768]);
  else if (i < 65536) wbb[i - 49152] = f2b(Wb[i - 49152]);
  else                wob[i - 65536] = f2b(Wo[i - 65536]);
}

// ---------------- Pass 1: partial KV/Ks per 1024-n chunk (MFMA; HBM-bound) -------------------------
__global__ __launch_bounds__(512, 4) void k_pass1(const float* __restrict__ t1,
    const float* __restrict__ t2, const float* __restrict__ t3, const float* __restrict__ fs,
    const u16* __restrict__ wkb, const u16* __restrict__ wvb,
    float* __restrict__ pkv, float* __restrict__ pks){
  __shared__ u16 Xl [64*128];    // 16384 B
  __shared__ u16 khl[128*64];    // 16384 B
  __shared__ u16 vl [128*64];    // 16384 B  -> 49152 B
  int bid = blockIdx.x;
  int ch = bid & 15, b = (bid >> 4) & 7, s = bid >> 7;
  int tid = threadIdx.x, lane = tid & 63;
  int w = rfl(tid >> 6), rb = w*16;
  int g = lane >> 4, m = lane & 15;
  const float* src = (s==0)?t1:(s==1)?t2:(s==2)?t3:fs;
  src += (size_t)b*128*N_SEQ + ch*1024;
  f32x4 kvacc = (f32x4){0.f,0.f,0.f,0.f};
  float ksump[4] = {0.f,0.f,0.f,0.f};
  #pragma unroll 1
  for (int tile = 0; tile < 16; ++tile){
    const float* sp = src + tile*64;
    #pragma unroll
    for (int rr = 0; rr < 8; ++rr){        // coalesced along n; packed u32 LDS writes
      int c = w*16 + rr*2;
      float f0 = sp[(size_t)c*N_SEQ + lane];
      float f1 = sp[(size_t)(c+1)*N_SEQ + lane];
      *reinterpret_cast<u32*>(&Xl[xidx(lane, c)]) = pk2(f0, f1);
    }
    __syncthreads();
    f32x4 kh[4], vv[4];
    #pragma unroll
    for (int nt = 0; nt < 4; ++nt){ kh[nt] = (f32x4){0.f,0.f,0.f,0.f}; vv[nt] = kh[nt]; }
    gemmW(wkb, rb + m, 128, 0, Xl, m, g, kh);
    gemmW(wvb, rb + m, 128, 0, Xl, m, g, vv);
    #pragma unroll
    for (int nt = 0; nt < 4; ++nt)
      #pragma unroll
      for (int r = 0; r < 4; ++r){
        float x = fmaxf(kh[nt][r], 0.f) + EPSF;   // kh = relu(.)+eps
        ksump[r] += x;
        khl[kidx(rb + 4*g + r, nt*16 + m)] = f2b(x);
        vl [kidx(rb + 4*g + r, nt*16 + m)] = f2b(vv[nt][r]);
      }
    __syncthreads();
    // KV_w += kh_w(16 x 64n) @ v_w^T : A[d][k=n], B[k=n][col=m-feat]
    #pragma unroll
    for (int ks2 = 0; ks2 < 2; ++ks2){
      const bf16x8 av = *reinterpret_cast<const bf16x8*>(&khl[kidx(rb+m, ks2*32 + g*8)]);
      const bf16x8 bv = *reinterpret_cast<const bf16x8*>(&vl [kidx(rb+m, ks2*32 + g*8)]);
      kvacc = MFMA(av, bv, kvacc);
    }
  }
  size_t pb = (((size_t)(ch*4 + s)*8 + b)*8 + w)*256;
  #pragma unroll
  for (int r = 0; r < 4; ++r)
    pkv[pb + (size_t)(4*g + r)*16 + m] = kvacc[r];
  #pragma unroll
  for (int r = 0; r < 4; ++r){
    float v2 = ksump[r];
    v2 += __shfl_xor(v2, 1); v2 += __shfl_xor(v2, 2);
    v2 += __shfl_xor(v2, 4); v2 += __shfl_xor(v2, 8);
    if (m == 0) pks[(((size_t)(ch*4 + s)*8 + b)*8 + w)*16 + 4*g + r] = v2;
  }
}

// ---------------- Reduce partials; emit KV as prepacked bf16 A-fragments ---------------------------
__global__ void k_reduce(const float* __restrict__ pkv, const float* __restrict__ pks,
                         u32* __restrict__ kvb, float* __restrict__ ksf){
  int i = blockIdx.x*256 + threadIdx.x;   // grid 144*256 = 36864
  if (i < 32768){
    int sA = i >> 7, r7 = i & 127;
    int gb = r7 >> 6, m = (r7 >> 2) & 15, t = r7 & 3;
    int d = gb*8 + 2*t;
    float a0 = 0.f, a1 = 0.f;
    #pragma unroll
    for (int ch = 0; ch < 16; ++ch){
      a0 += pkv[(size_t)ch*65536 + sA*256 + d*16 + m];
      a1 += pkv[(size_t)ch*65536 + sA*256 + (d+1)*16 + m];
    }
    kvb[i] = pk2(a0, a1);
  } else {
    int j = i - 32768;   // < 4096
    float a = 0.f;
    #pragma unroll
    for (int ch = 0; ch < 16; ++ch) a += pks[(size_t)ch*4096 + j];
    ksf[j] = a;
  }
}

// ---------------- Pass 2: 2x2-blocked waves (32r x 32c), halved LDS B-read traffic -----------------
__global__ __launch_bounds__(512, 4) void k_pass2(const float* __restrict__ t1,
    const float* __restrict__ t2, const float* __restrict__ t3, const float* __restrict__ fs,
    const u16* __restrict__ wqb, const u16* __restrict__ wbb, const u16* __restrict__ wob,
    const u32* __restrict__ kvb, const float* __restrict__ ksf, float* __restrict__ outp){
  __shared__ u16 Xl[64*128];       // 16384 B
  __shared__ u16 Ul[64*128];       // 16384 B
  __shared__ u16 Qt[8*64*QTS];     // 24576 B -> total 57344 B
  int bid = blockIdx.x;
  int b = bid >> 8, n0 = (bid & 255) * 64;
  int tid = threadIdx.x, lane = tid & 63;
  int w = rfl(tid >> 6);
  int W = w >> 1, CB = (w & 1) * 32, rb32 = W * 32;   // wave: rows rb32..+31, cols CB..+31
  int g = lane >> 4, m = lane & 15;
  f32x4 oacc[2][2];
  #pragma unroll
  for (int rt = 0; rt < 2; ++rt)
    #pragma unroll
    for (int ct = 0; ct < 2; ++ct) oacc[rt][ct] = (f32x4){0.f,0.f,0.f,0.f};

  #pragma unroll 1
  for (int i = 0; i < 3; ++i){
    const float* src = (i==0)?t1:(i==1)?t2:t3;
    int s1 = (i==0)?1:0, s2 = (i==2)?1:2;
    // ---- write t_i tile to Xl (bf16), 2x2 ownership ----
    #pragma unroll
    for (int rt = 0; rt < 2; ++rt)
      #pragma unroll
      for (int ct = 0; ct < 2; ++ct){
        int f = rb32 + rt*16 + 4*g;
        int n = n0 + CB + ct*16 + m;
        float v0 = src[(size_t)(b*128 + f + 0)*N_SEQ + n];
        float v1 = src[(size_t)(b*128 + f + 1)*N_SEQ + n];
        float v2 = src[(size_t)(b*128 + f + 2)*N_SEQ + n];
        float v3 = src[(size_t)(b*128 + f + 3)*N_SEQ + n];
        *reinterpret_cast<uint2*>(&Xl[xidx(CB + ct*16 + m, f)]) =
          make_uint2(pk2(v0, v1), pk2(v2, v3));
      }
    __syncthreads();
    stage<2>(Xl, Ul, Qt, wqb, wbb, kvb, ksf, s1, s2, b, W, CB, rb32, g, m);  // stage A
    stage<1>(Xl, Ul, Qt, wqb, wbb, kvb, ksf, 3, 3, b, W, CB, rb32, g, m);    // stage B
    // acc += Wout[:, i*128 : i*128+128] @ t_if
    gemm22(wob, rb32, 384, i*128, Xl, CB, m, g, oacc);
    __syncthreads();   // before next i overwrites Xl
  }
  #pragma unroll
  for (int rt = 0; rt < 2; ++rt)
    #pragma unroll
    for (int ct = 0; ct < 2; ++ct)
      #pragma unroll
      for (int r = 0; r < 4; ++r){
        size_t idx = (size_t)(b*128 + rb32 + rt*16 + 4*g + r)*N_SEQ + n0 + CB + ct*16 + m;
        outp[idx] = oacc[rt][ct][r] + fs[idx];
      }
}

extern "C" void kernel_launch(void* const* d_in, const int* in_sizes, int n_in,
                              void* d_out, int out_size, void* d_ws, size_t ws_size,
                              hipStream_t stream){
  const float* t1 = (const float*)d_in[0];
  const float* t2 = (const float*)d_in[1];
  const float* t3 = (const float*)d_in[2];
  const float* fs = (const float*)d_in[3];
  const float* Wq = (const float*)d_in[4];
  const float* Wk = (const float*)d_in[5];
  const float* Wv = (const float*)d_in[6];
  const float* Wb = (const float*)d_in[7];
  const float* Wo = (const float*)d_in[8];
  float* outp = (float*)d_out;
  float* ws = (float*)d_ws;
  // ws layout (float units):
  //   pkv [16*65536] | pks [16*4096] | ksf [4096] | kvb [32768 u32]
  //   | wqb,wkb,wvb,wbb [4 * 8192] | wob [24576]     (bf16 halves in float-sized slots)
  float* pkv = ws;
  float* pks = ws + 16*65536;
  float* ksf = ws + 16*65536 + 16*4096;
  u32*  kvb  = (u32*)(ksf + 4096);
  u16*  wqb  = (u16*)(kvb + 32768);
  u16*  wkb  = wqb + 16384;
  u16*  wvb  = wkb + 16384;
  u16*  wbb  = wvb + 16384;
  u16*  wob  = wbb + 16384;   // 49152 u16

  k_prepack<<<dim3(448),  dim3(256), 0, stream>>>(Wq, Wk, Wv, Wb, Wo, wqb, wkb, wvb, wbb, wob);
  k_pass1  <<<dim3(512),  dim3(512), 0, stream>>>(t1, t2, t3, fs, wkb, wvb, pkv, pks);
  k_reduce <<<dim3(144),  dim3(256), 0, stream>>>(pkv, pks, kvb, ksf);
  k_pass2  <<<dim3(2048), dim3(512), 0, stream>>>(t1, t2, t3, fs, wqb, wbb, wob, kvb, ksf, outp);
}

// Round 16
// 205.544 us; speedup vs baseline: 2.3901x; 2.3901x over previous
//
#include <hip/hip_runtime.h>
#include <hip/hip_bf16.h>

// B=8, C=128, N=16384, NH=8, HD=16, D=128
#define N_SEQ 16384
#define EPSF 1e-6f

typedef unsigned short u16;
typedef unsigned int   u32;
typedef __attribute__((ext_vector_type(8))) __bf16 bf16x8;
typedef __attribute__((ext_vector_type(4))) float  f32x4;

union B8 { u32 w[4]; bf16x8 v; };

__device__ __forceinline__ int rfl(int x){ return __builtin_amdgcn_readfirstlane(x); }
__device__ __forceinline__ u16 f2b(float x){
  union { __hip_bfloat16 h; u16 u; } c; c.h = __float2bfloat16(x); return c.u;
}
__device__ __forceinline__ u32 pk2(float a, float b){
  return (u32)f2b(a) | ((u32)f2b(b) << 16);
}
__device__ __forceinline__ float bf2f(u16 v){ return __uint_as_float(((u32)v) << 16); }
#define MFMA(a,b,c) __builtin_amdgcn_mfma_f32_16x16x32_bf16((a),(b),(c),0,0,0)

// Swizzled LDS indexers (u16 units): linear rows, idx ^= (row&7)<<3.
__device__ __forceinline__ int xidx(int n, int f){ return n*128 + (f ^ ((n & 7) << 3)); } // [64 n][128 f]
__device__ __forceinline__ int kidx(int d, int n){ return d*64  + (n ^ ((d & 7) << 3)); } // [128 d][64 n]

#define QTS 24   // u16 stride of Qt rows (48B: 16B-aligned for ds_read_b128)

// q[nt] += W @ X.  W: prepacked bf16 row-major (ldw u16/row) — A-frags load directly, no cvt.
__device__ __forceinline__ void gemmW(const u16* __restrict__ Wb, int row, int ldw, int koff,
                                      const u16* __restrict__ Xl, int m, int g, f32x4 q[4]){
  #pragma unroll
  for (int ks = 0; ks < 4; ++ks){
    const bf16x8 av = *reinterpret_cast<const bf16x8*>(&Wb[(size_t)row*ldw + koff + ks*32 + g*8]);
    #pragma unroll
    for (int nt = 0; nt < 4; ++nt){
      const bf16x8 bv = *reinterpret_cast<const bf16x8*>(&Xl[xidx(nt*16+m, ks*32 + g*8)]);
      q[nt] = MFMA(av, bv, q[nt]);
    }
  }
}

// One attention+Wback stage: T += Wback @ [ sum_s z_s * (qh @ KV_s) ],  qh = relu(Wq@T)+eps.
// T's master copy lives as bf16 in Xl (each element owned by one thread -> safe RMW).
// PV B-fragments come from a per-head LDS transpose buffer Qt (within-wave prod/cons, no barrier).
template<int NSRC>
__device__ __forceinline__ void stage(u16* Xl, u16* Ul, u16* Qt,
    const u16* __restrict__ wqb, const u16* __restrict__ wbb,
    const u32* __restrict__ kvb, const float* __restrict__ ksf,
    int s1, int s2, int b, int w, int g, int m, int rb){
  const int sA = ((s1*8 + b)*8 + w);
  const int sB = ((s2*8 + b)*8 + w);
  float4 ksA = *reinterpret_cast<const float4*>(ksf + sA*16 + 4*g);
  float4 ksB = ksA;
  // KV A-fragment: prepacked pairs, one dwordx4 per source
  B8 kA, kB;
  uint4 ka4 = *reinterpret_cast<const uint4*>(&kvb[sA*128 + (g&1)*64 + m*4]);
  kA.w[0]=ka4.x; kA.w[1]=ka4.y; kA.w[2]=ka4.z; kA.w[3]=ka4.w;
  if (NSRC == 2){
    ksB = *reinterpret_cast<const float4*>(ksf + sB*16 + 4*g);
    uint4 kb4 = *reinterpret_cast<const uint4*>(&kvb[sB*128 + (g&1)*64 + m*4]);
    kB.w[0]=kb4.x; kB.w[1]=kb4.y; kB.w[2]=kb4.z; kB.w[3]=kb4.w;
  }
  // qh = relu(Wq @ X) + eps  (C/D regs: row rb+4g+r, col nt*16+m)
  f32x4 q[4];
  #pragma unroll
  for (int nt = 0; nt < 4; ++nt) q[nt] = (f32x4){0.f,0.f,0.f,0.f};
  gemmW(wqb, rb + m, 128, 0, Xl, m, g, q);
  #pragma unroll
  for (int nt = 0; nt < 4; ++nt)
    #pragma unroll
    for (int r = 0; r < 4; ++r) q[nt][r] = fmaxf(q[nt][r], 0.f) + EPSF;
  // z_s(n, h=w) = 1/(qh . Ks_s + eps): partial over own 4 rows, reduce over lane-groups
  float z1[4], z2[4];
  #pragma unroll
  for (int nt = 0; nt < 4; ++nt){
    float p = q[nt][0]*ksA.x + q[nt][1]*ksA.y + q[nt][2]*ksA.z + q[nt][3]*ksA.w;
    p += __shfl_xor(p, 16); p += __shfl_xor(p, 32);
    z1[nt] = 1.0f / (p + EPSF);
  }
  if (NSRC == 2){
    #pragma unroll
    for (int nt = 0; nt < 4; ++nt){
      float p = q[nt][0]*ksB.x + q[nt][1]*ksB.y + q[nt][2]*ksB.z + q[nt][3]*ksB.w;
      p += __shfl_xor(p, 16); p += __shfl_xor(p, 32);
      z2[nt] = 1.0f / (p + EPSF);
    }
  }
  // qh^T into Qt[head][n][d] (bf16, stride QTS): lane owns d=4g..4g+3 at col n=nt*16+m
  u16* qrow = Qt + w*(64*QTS);
  #pragma unroll
  for (int nt = 0; nt < 4; ++nt)
    *reinterpret_cast<uint2*>(&qrow[(nt*16+m)*QTS + 4*g]) =
      make_uint2(pk2(q[nt][0], q[nt][1]), pk2(q[nt][2], q[nt][3]));
  // PV: B[k=d][col] = Qt[n=nt*16+col][d=g*8+j] (g<2; k>=16 zero-padded)
  #pragma unroll
  for (int nt = 0; nt < 4; ++nt){
    B8 bb;
    if (g < 2) bb.v = *reinterpret_cast<const bf16x8*>(&qrow[(nt*16+m)*QTS + g*8]);
    else { bb.w[0]=0u; bb.w[1]=0u; bb.w[2]=0u; bb.w[3]=0u; }
    const f32x4 z4 = (f32x4){0.f,0.f,0.f,0.f};
    f32x4 S1 = MFMA(kA.v, bb.v, z4);
    f32x4 Uv = S1 * z1[nt];
    if (NSRC == 2){
      f32x4 S2 = MFMA(kB.v, bb.v, z4);
      Uv += S2 * z2[nt];
    }
    *reinterpret_cast<uint2*>(&Ul[xidx(nt*16+m, rb + 4*g)]) =
      make_uint2(pk2(Uv[0], Uv[1]), pk2(Uv[2], Uv[3]));
  }
  // preload old T into the Wback accumulator (MFMA C-in does the add); Xl stable until we store
  f32x4 t4[4];
  #pragma unroll
  for (int nt = 0; nt < 4; ++nt){
    uint2 old = *reinterpret_cast<const uint2*>(&Xl[xidx(nt*16+m, rb + 4*g)]);
    t4[nt][0] = bf2f((u16)(old.x & 0xffffu));
    t4[nt][1] = bf2f((u16)(old.x >> 16));
    t4[nt][2] = bf2f((u16)(old.y & 0xffffu));
    t4[nt][3] = bf2f((u16)(old.y >> 16));
  }
  __syncthreads();
  // T += Wback @ U
  gemmW(wbb, rb + m, 128, 0, Ul, m, g, t4);
  #pragma unroll
  for (int nt = 0; nt < 4; ++nt)
    *reinterpret_cast<uint2*>(&Xl[xidx(nt*16+m, rb + 4*g)]) =
      make_uint2(pk2(t4[nt][0], t4[nt][1]), pk2(t4[nt][2], t4[nt][3]));
  __syncthreads();
}

// ---------------- Prepack: all weights -> bf16 row-major (MFMA-ready) ------------------------------
__global__ void k_prepack(const float* __restrict__ Wq, const float* __restrict__ Wk,
                          const float* __restrict__ Wv, const float* __restrict__ Wb,
                          const float* __restrict__ Wo,
                          u16* __restrict__ wqb, u16* __restrict__ wkb, u16* __restrict__ wvb,
                          u16* __restrict__ wbb, u16* __restrict__ wob){
  int i = blockIdx.x*256 + threadIdx.x;     // grid 448*256 = 114688
  if      (i < 16384) wqb[i]         = f2b(Wq[i]);
  else if (i < 32768) wkb[i - 16384] = f2b(Wk[i - 16384]);
  else if (i < 49152) wvb[i - 32768] = f2b(Wv[i - 32768]);
  else if (i < 65536) wbb[i - 49152] = f2b(Wb[i - 49152]);
  else                wob[i - 65536] = f2b(Wo[i - 65536]);
}

// ---------------- Pass 1: partial KV/Ks per 1024-n chunk (MFMA; HBM-bound) -------------------------
__global__ __launch_bounds__(512, 4) void k_pass1(const float* __restrict__ t1,
    const float* __restrict__ t2, const float* __restrict__ t3, const float* __restrict__ fs,
    const u16* __restrict__ wkb, const u16* __restrict__ wvb,
    float* __restrict__ pkv, float* __restrict__ pks){
  __shared__ u16 Xl [64*128];    // 16384 B
  __shared__ u16 khl[128*64];    // 16384 B
  __shared__ u16 vl [128*64];    // 16384 B  -> 49152 B
  int bid = blockIdx.x;
  int ch = bid & 15, b = (bid >> 4) & 7, s = bid >> 7;
  int tid = threadIdx.x, lane = tid & 63;
  int w = rfl(tid >> 6), rb = w*16;
  int g = lane >> 4, m = lane & 15;
  const float* src = (s==0)?t1:(s==1)?t2:(s==2)?t3:fs;
  src += (size_t)b*128*N_SEQ + ch*1024;
  f32x4 kvacc = (f32x4){0.f,0.f,0.f,0.f};
  float ksump[4] = {0.f,0.f,0.f,0.f};
  #pragma unroll 1
  for (int tile = 0; tile < 16; ++tile){
    const float* sp = src + tile*64;
    #pragma unroll
    for (int rr = 0; rr < 8; ++rr){        // coalesced along n; packed u32 LDS writes
      int c = w*16 + rr*2;
      float f0 = sp[(size_t)c*N_SEQ + lane];
      float f1 = sp[(size_t)(c+1)*N_SEQ + lane];
      *reinterpret_cast<u32*>(&Xl[xidx(lane, c)]) = pk2(f0, f1);
    }
    __syncthreads();
    f32x4 kh[4], vv[4];
    #pragma unroll
    for (int nt = 0; nt < 4; ++nt){ kh[nt] = (f32x4){0.f,0.f,0.f,0.f}; vv[nt] = kh[nt]; }
    gemmW(wkb, rb + m, 128, 0, Xl, m, g, kh);
    gemmW(wvb, rb + m, 128, 0, Xl, m, g, vv);
    #pragma unroll
    for (int nt = 0; nt < 4; ++nt)
      #pragma unroll
      for (int r = 0; r < 4; ++r){
        float x = fmaxf(kh[nt][r], 0.f) + EPSF;   // kh = relu(.)+eps
        ksump[r] += x;
        khl[kidx(rb + 4*g + r, nt*16 + m)] = f2b(x);
        vl [kidx(rb + 4*g + r, nt*16 + m)] = f2b(vv[nt][r]);
      }
    __syncthreads();
    // KV_w += kh_w(16 x 64n) @ v_w^T : A[d][k=n], B[k=n][col=m-feat]
    #pragma unroll
    for (int ks2 = 0; ks2 < 2; ++ks2){
      const bf16x8 av = *reinterpret_cast<const bf16x8*>(&khl[kidx(rb+m, ks2*32 + g*8)]);
      const bf16x8 bv = *reinterpret_cast<const bf16x8*>(&vl [kidx(rb+m, ks2*32 + g*8)]);
      kvacc = MFMA(av, bv, kvacc);
    }
  }
  size_t pb = (((size_t)(ch*4 + s)*8 + b)*8 + w)*256;
  #pragma unroll
  for (int r = 0; r < 4; ++r)
    pkv[pb + (size_t)(4*g + r)*16 + m] = kvacc[r];
  #pragma unroll
  for (int r = 0; r < 4; ++r){
    float v2 = ksump[r];
    v2 += __shfl_xor(v2, 1); v2 += __shfl_xor(v2, 2);
    v2 += __shfl_xor(v2, 4); v2 += __shfl_xor(v2, 8);
    if (m == 0) pks[(((size_t)(ch*4 + s)*8 + b)*8 + w)*16 + 4*g + r] = v2;
  }
}

// ---------------- Reduce partials; emit KV as prepacked bf16 A-fragments ---------------------------
__global__ void k_reduce(const float* __restrict__ pkv, const float* __restrict__ pks,
                         u32* __restrict__ kvb, float* __restrict__ ksf){
  int i = blockIdx.x*256 + threadIdx.x;   // grid 144*256 = 36864
  if (i < 32768){
    int sA = i >> 7, r7 = i & 127;
    int gb = r7 >> 6, m = (r7 >> 2) & 15, t = r7 & 3;
    int d = gb*8 + 2*t;
    float a0 = 0.f, a1 = 0.f;
    #pragma unroll
    for (int ch = 0; ch < 16; ++ch){
      a0 += pkv[(size_t)ch*65536 + sA*256 + d*16 + m];
      a1 += pkv[(size_t)ch*65536 + sA*256 + (d+1)*16 + m];
    }
    kvb[i] = pk2(a0, a1);
  } else {
    int j = i - 32768;   // < 4096
    float a = 0.f;
    #pragma unroll
    for (int ch = 0; ch < 16; ++ch) a += pks[(size_t)ch*4096 + j];
    ksf[j] = a;
  }
}

// ---------------- Pass 2: fused per-n pipeline, all GEMMs on MFMA ----------------------------------
__global__ __launch_bounds__(512, 4) void k_pass2(const float* __restrict__ t1,
    const float* __restrict__ t2, const float* __restrict__ t3, const float* __restrict__ fs,
    const u16* __restrict__ wqb, const u16* __restrict__ wbb, const u16* __restrict__ wob,
    const u32* __restrict__ kvb, const float* __restrict__ ksf, float* __restrict__ outp){
  __shared__ u16 Xl[64*128];       // 16384 B
  __shared__ u16 Ul[64*128];       // 16384 B
  __shared__ u16 Qt[8*64*QTS];     // 24576 B -> total 57344 B
  int bid = blockIdx.x;
  int b = bid >> 8, n0 = (bid & 255) * 64;
  int tid = threadIdx.x, lane = tid & 63;
  int w = rfl(tid >> 6), rb = w*16;
  int g = lane >> 4, m = lane & 15;
  f32x4 oacc[4];
  #pragma unroll
  for (int nt = 0; nt < 4; ++nt) oacc[nt] = (f32x4){0.f,0.f,0.f,0.f};

  #pragma unroll 1
  for (int i = 0; i < 3; ++i){
    const float* src = (i==0)?t1:(i==1)?t2:t3;
    int s1 = (i==0)?1:0, s2 = (i==2)?1:2;
    #pragma unroll
    for (int nt = 0; nt < 4; ++nt){
      float f0 = src[(size_t)(b*128 + rb + 4*g + 0)*N_SEQ + n0 + nt*16 + m];
      float f1 = src[(size_t)(b*128 + rb + 4*g + 1)*N_SEQ + n0 + nt*16 + m];
      float f2 = src[(size_t)(b*128 + rb + 4*g + 2)*N_SEQ + n0 + nt*16 + m];
      float f3 = src[(size_t)(b*128 + rb + 4*g + 3)*N_SEQ + n0 + nt*16 + m];
      *reinterpret_cast<uint2*>(&Xl[xidx(nt*16+m, rb + 4*g)]) =
        make_uint2(pk2(f0, f1), pk2(f2, f3));
    }
    __syncthreads();
    stage<2>(Xl, Ul, Qt, wqb, wbb, kvb, ksf, s1, s2, b, w, g, m, rb);  // stage A
    stage<1>(Xl, Ul, Qt, wqb, wbb, kvb, ksf, 3, 3, b, w, g, m, rb);    // stage B
    // acc += Wout[:, i*128 : i*128+128] @ t_if
    gemmW(wob, rb + m, 384, i*128, Xl, m, g, oacc);
    __syncthreads();   // before next i overwrites Xl
  }
  #pragma unroll
  for (int nt = 0; nt < 4; ++nt)
    #pragma unroll
    for (int r = 0; r < 4; ++r){
      size_t idx = (size_t)(b*128 + rb + 4*g + r)*N_SEQ + n0 + nt*16 + m;
      outp[idx] = oacc[nt][r] + fs[idx];
    }
}

extern "C" void kernel_launch(void* const* d_in, const int* in_sizes, int n_in,
                              void* d_out, int out_size, void* d_ws, size_t ws_size,
                              hipStream_t stream){
  const float* t1 = (const float*)d_in[0];
  const float* t2 = (const float*)d_in[1];
  const float* t3 = (const float*)d_in[2];
  const float* fs = (const float*)d_in[3];
  const float* Wq = (const float*)d_in[4];
  const float* Wk = (const float*)d_in[5];
  const float* Wv = (const float*)d_in[6];
  const float* Wb = (const float*)d_in[7];
  const float* Wo = (const float*)d_in[8];
  float* outp = (float*)d_out;
  float* ws = (float*)d_ws;
  // ws layout (float units):
  //   pkv [16*65536] | pks [16*4096] | ksf [4096] | kvb [32768 u32]
  //   | wqb,wkb,wvb,wbb [4 * 8192] | wob [24576]     (bf16 halves in float-sized slots)
  float* pkv = ws;
  float* pks = ws + 16*65536;
  float* ksf = ws + 16*65536 + 16*4096;
  u32*  kvb  = (u32*)(ksf + 4096);
  u16*  wqb  = (u16*)(kvb + 32768);
  u16*  wkb  = wqb + 16384;
  u16*  wvb  = wkb + 16384;
  u16*  wbb  = wvb + 16384;
  u16*  wob  = wbb + 16384;   // 49152 u16

  k_prepack<<<dim3(448),  dim3(256), 0, stream>>>(Wq, Wk, Wv, Wb, Wo, wqb, wkb, wvb, wbb, wob);
  k_pass1  <<<dim3(512),  dim3(512), 0, stream>>>(t1, t2, t3, fs, wkb, wvb, pkv, pks);
  k_reduce <<<dim3(144),  dim3(256), 0, stream>>>(pkv, pks, kvb, ksf);
  k_pass2  <<<dim3(2048), dim3(512), 0, stream>>>(t1, t2, t3, fs, wqb, wbb, wob, kvb, ksf, outp);
}